// Round 1
// baseline (362.550 us; speedup 1.0000x reference)
//
#include <hip/hip_runtime.h>

typedef unsigned short u16;
typedef __attribute__((ext_vector_type(8))) short short8;
typedef __attribute__((ext_vector_type(4))) float f32x4;

// ---------------------------------------------------------------------------
// Constants for this problem
// ---------------------------------------------------------------------------
#define M_TOK 8192
#define N_OUT 4096
#define K_IN  4096

// fp32 -> bf16 round-to-nearest-even (inputs are finite normals; no NaN path)
static __device__ __forceinline__ u16 f2bf(float f) {
    unsigned u = __float_as_uint(f);
    u += 0x7FFFu + ((u >> 16) & 1u);
    return (u16)(u >> 16);
}

// ---------------------------------------------------------------------------
// Kernel 1: convert x (fp32) -> bf16, vectorized 8 elems/thread/iter
// ---------------------------------------------------------------------------
__global__ __launch_bounds__(256) void cvt_x_kernel(const float* __restrict__ x,
                                                    u16* __restrict__ xb, int n8) {
    int idx = blockIdx.x * blockDim.x + threadIdx.x;
    int stride = gridDim.x * blockDim.x;
    for (int i = idx; i < n8; i += stride) {
        const float4* p = (const float4*)(x + (size_t)i * 8);
        float4 a = p[0];
        float4 b = p[1];
        union { u16 s[8]; uint4 v; } o;
        o.s[0] = f2bf(a.x); o.s[1] = f2bf(a.y); o.s[2] = f2bf(a.z); o.s[3] = f2bf(a.w);
        o.s[4] = f2bf(b.x); o.s[5] = f2bf(b.y); o.s[6] = f2bf(b.z); o.s[7] = f2bf(b.w);
        *(uint4*)(xb + (size_t)i * 8) = o.v;
    }
}

// ---------------------------------------------------------------------------
// Kernel 2: unpack int4 weights (one byte per int32) -> bf16 rows [O][I].
// Scale is NOT applied here (kept int-exact in bf16; scale in GEMM epilogue).
// Each iter: 4 int32 = 4 bytes = 8 weights -> 16B store.
// ---------------------------------------------------------------------------
__global__ __launch_bounds__(256) void unpack_w_kernel(const int* __restrict__ pw,
                                                       u16* __restrict__ wb, int n4) {
    int idx = blockIdx.x * blockDim.x + threadIdx.x;
    int stride = gridDim.x * blockDim.x;
    for (int i = idx; i < n4; i += stride) {
        int4 p = *(const int4*)(pw + (size_t)i * 4);
        union { u16 s[8]; uint4 v; } o;
        int b;
        b = p.x; o.s[0] = f2bf((float)((b & 15) - 8)); o.s[1] = f2bf((float)(((b >> 4) & 15) - 8));
        b = p.y; o.s[2] = f2bf((float)((b & 15) - 8)); o.s[3] = f2bf((float)(((b >> 4) & 15) - 8));
        b = p.z; o.s[4] = f2bf((float)((b & 15) - 8)); o.s[5] = f2bf((float)(((b >> 4) & 15) - 8));
        b = p.w; o.s[6] = f2bf((float)((b & 15) - 8)); o.s[7] = f2bf((float)(((b >> 4) & 15) - 8));
        *(uint4*)(wb + (size_t)i * 8) = o.v;
    }
}

// ---------------------------------------------------------------------------
// Kernel 3: bf16 GEMM, C[n][o] = scale[o] * sum_k A[n][k] * B[o][k]
// m97 structure: 128x128 tile, BK=32, 4 waves, 4x4 16x16x32 fragments/wave,
// global_load_lds width=16 staging, 2-barrier K-loop.
// ---------------------------------------------------------------------------
#define BM 128
#define BN 128
#define BK 32

static __device__ __forceinline__ void gload_lds16(const u16* g, u16* l) {
    __builtin_amdgcn_global_load_lds(
        (const __attribute__((address_space(1))) void*)g,
        (__attribute__((address_space(3))) void*)l,
        16, 0, 0);
}

__global__ __launch_bounds__(256) void gemm_bf16_kernel(const u16* __restrict__ A,
                                                        const u16* __restrict__ B,
                                                        const float* __restrict__ scale,
                                                        float* __restrict__ C) {
    __shared__ __align__(16) u16 sA[BM * BK];
    __shared__ __align__(16) u16 sB[BN * BK];

    // XCD-aware swizzle: nwg = 64*32 = 2048, divisible by 8.
    int wg = blockIdx.x;
    int swz = (wg & 7) * (2048 / 8) + (wg >> 3);
    int bm = swz / (N_OUT / BN);   // 0..63
    int bn = swz % (N_OUT / BN);   // 0..31

    int t = threadIdx.x;
    int lane = t & 63;
    int wid = t >> 6;
    int wr = wid >> 1;             // wave row 0..1 (64-row slab)
    int wc = wid & 1;              // wave col 0..1 (64-col slab)

    const u16* Ablk = A + (size_t)(bm * BM) * K_IN;
    const u16* Bblk = B + (size_t)(bn * BN) * K_IN;

    // staging map: thread t covers tile row (t>>2) (+64 for 2nd issue),
    // k-cols (t&3)*8 .. +8 -> LDS byte offset = t*16 (linear, wave-uniform base)
    int srow = t >> 2;             // 0..63
    int scol = (t & 3) * 8;        // 0,8,16,24

    f32x4 acc[4][4] = {};

    // fragment read addresses (constant across K-loop)
    int arow = wr * 64 + (lane & 15);
    int brow = wc * 64 + (lane & 15);
    int kfrag = (lane >> 4) * 8;

    for (int kt = 0; kt < K_IN / BK; ++kt) {
        int k0 = kt * BK;
        gload_lds16(&Ablk[(size_t)srow * K_IN + k0 + scol],        &sA[srow * BK + scol]);
        gload_lds16(&Ablk[(size_t)(64 + srow) * K_IN + k0 + scol], &sA[(64 + srow) * BK + scol]);
        gload_lds16(&Bblk[(size_t)srow * K_IN + k0 + scol],        &sB[srow * BK + scol]);
        gload_lds16(&Bblk[(size_t)(64 + srow) * K_IN + k0 + scol], &sB[(64 + srow) * BK + scol]);
        __syncthreads();

        short8 af[4], bf[4];
#pragma unroll
        for (int m = 0; m < 4; ++m)
            af[m] = *(const short8*)&sA[(arow + m * 16) * BK + kfrag];
#pragma unroll
        for (int n = 0; n < 4; ++n)
            bf[n] = *(const short8*)&sB[(brow + n * 16) * BK + kfrag];

#pragma unroll
        for (int m = 0; m < 4; ++m)
#pragma unroll
            for (int n = 0; n < 4; ++n)
                acc[m][n] = __builtin_amdgcn_mfma_f32_16x16x32_bf16(af[m], bf[n], acc[m][n], 0, 0, 0);

        __syncthreads();
    }

    // epilogue: C/D layout col = lane&15, row = (lane>>4)*4 + reg
    float sc[4];
#pragma unroll
    for (int n = 0; n < 4; ++n)
        sc[n] = scale[bn * BN + wc * 64 + n * 16 + (lane & 15)];

#pragma unroll
    for (int m = 0; m < 4; ++m) {
        int grow0 = bm * BM + wr * 64 + m * 16 + (lane >> 4) * 4;
#pragma unroll
        for (int n = 0; n < 4; ++n) {
            int gcol = bn * BN + wc * 64 + n * 16 + (lane & 15);
#pragma unroll
            for (int j = 0; j < 4; ++j)
                C[(size_t)(grow0 + j) * N_OUT + gcol] = acc[m][n][j] * sc[n];
        }
    }
}

// ---------------------------------------------------------------------------
// Fallback (only if workspace too small): fused fp32 LDS-tiled GEMM, 64x64 tile
// ---------------------------------------------------------------------------
__global__ __launch_bounds__(256) void gemm_fb_kernel(const float* __restrict__ X,
                                                      const int* __restrict__ PW,
                                                      const float* __restrict__ S,
                                                      float* __restrict__ C) {
    __shared__ float sx[64][33];
    __shared__ float sw[64][33];
    int bm = blockIdx.x / (N_OUT / 64);
    int bn = blockIdx.x % (N_OUT / 64);
    int t = threadIdx.x;
    int r = t >> 2, c8 = (t & 3) * 8;
    int tx = t & 15, ty = t >> 4;
    float acc[4][4] = {};
    for (int k0 = 0; k0 < K_IN; k0 += 32) {
        const float* xs = X + (size_t)(bm * 64 + r) * K_IN + k0 + c8;
#pragma unroll
        for (int j = 0; j < 8; ++j) sx[r][c8 + j] = xs[j];
        const int* ps = PW + ((size_t)(bn * 64 + r) * K_IN + k0 + c8) / 2;
#pragma unroll
        for (int j = 0; j < 4; ++j) {
            int b = ps[j];
            sw[r][c8 + 2 * j]     = (float)((b & 15) - 8);
            sw[r][c8 + 2 * j + 1] = (float)(((b >> 4) & 15) - 8);
        }
        __syncthreads();
#pragma unroll
        for (int kk = 0; kk < 32; ++kk) {
            float a[4], w[4];
#pragma unroll
            for (int i = 0; i < 4; ++i) a[i] = sx[ty * 4 + i][kk];
#pragma unroll
            for (int j = 0; j < 4; ++j) w[j] = sw[tx * 4 + j][kk];
#pragma unroll
            for (int i = 0; i < 4; ++i)
#pragma unroll
                for (int j = 0; j < 4; ++j) acc[i][j] += a[i] * w[j];
        }
        __syncthreads();
    }
#pragma unroll
    for (int i = 0; i < 4; ++i) {
        int gr = bm * 64 + ty * 4 + i;
#pragma unroll
        for (int j = 0; j < 4; ++j) {
            int gc = bn * 64 + tx * 4 + j;
            C[(size_t)gr * N_OUT + gc] = acc[i][j] * S[gc];
        }
    }
}

// ---------------------------------------------------------------------------
// Entry point
// ---------------------------------------------------------------------------
extern "C" void kernel_launch(void* const* d_in, const int* in_sizes, int n_in,
                              void* d_out, int out_size, void* d_ws, size_t ws_size,
                              hipStream_t stream) {
    const float* x  = (const float*)d_in[0];
    const int*   pw = (const int*)d_in[1];
    const float* sc = (const float*)d_in[2];
    float* out = (float*)d_out;

    const size_t xb_elems = (size_t)M_TOK * K_IN;           // 33.5M bf16 = 67 MB
    const size_t wb_elems = (size_t)N_OUT * K_IN;           // 16.8M bf16 = 33.5 MB
    const size_t need = (xb_elems + wb_elems) * sizeof(u16);

    if (ws_size >= need) {
        u16* xb = (u16*)d_ws;
        u16* wb = xb + xb_elems;
        cvt_x_kernel<<<dim3(2048), dim3(256), 0, stream>>>(x, xb, (int)(xb_elems / 8));
        unpack_w_kernel<<<dim3(2048), dim3(256), 0, stream>>>(pw, wb, (int)(wb_elems / 8));
        gemm_bf16_kernel<<<dim3((M_TOK / BM) * (N_OUT / BN)), dim3(256), 0, stream>>>(xb, wb, sc, out);
    } else {
        gemm_fb_kernel<<<dim3((M_TOK / 64) * (N_OUT / 64)), dim3(256), 0, stream>>>(x, pw, sc, out);
    }
}

// Round 2
// 270.238 us; speedup vs baseline: 1.3416x; 1.3416x over previous
//
#include <hip/hip_runtime.h>

typedef unsigned short u16;
typedef __attribute__((ext_vector_type(8))) short short8;
typedef __attribute__((ext_vector_type(4))) float f32x4;

#define M_TOK 8192
#define N_OUT 4096
#define K_IN  4096
#define NT    (K_IN / 64)    // 64 K-tiles of BK=64

// fp32 -> bf16 round-to-nearest-even
static __device__ __forceinline__ u16 f2bf(float f) {
    unsigned u = __float_as_uint(f);
    u += 0x7FFFu + ((u >> 16) & 1u);
    return (u16)(u >> 16);
}

// ---------------------------------------------------------------------------
// Kernel 1: x fp32 -> bf16
// ---------------------------------------------------------------------------
__global__ __launch_bounds__(256) void cvt_x_kernel(const float* __restrict__ x,
                                                    u16* __restrict__ xb, int n8) {
    int idx = blockIdx.x * blockDim.x + threadIdx.x;
    int stride = gridDim.x * blockDim.x;
    for (int i = idx; i < n8; i += stride) {
        const float4* p = (const float4*)(x + (size_t)i * 8);
        float4 a = p[0];
        float4 b = p[1];
        union { u16 s[8]; uint4 v; } o;
        o.s[0] = f2bf(a.x); o.s[1] = f2bf(a.y); o.s[2] = f2bf(a.z); o.s[3] = f2bf(a.w);
        o.s[4] = f2bf(b.x); o.s[5] = f2bf(b.y); o.s[6] = f2bf(b.z); o.s[7] = f2bf(b.w);
        *(uint4*)(xb + (size_t)i * 8) = o.v;
    }
}

// ---------------------------------------------------------------------------
// Kernel 2: unpack int4 (byte-per-int32) -> bf16 [O][I]
// ---------------------------------------------------------------------------
__global__ __launch_bounds__(256) void unpack_w_kernel(const int* __restrict__ pw,
                                                       u16* __restrict__ wb, int n4) {
    int idx = blockIdx.x * blockDim.x + threadIdx.x;
    int stride = gridDim.x * blockDim.x;
    for (int i = idx; i < n4; i += stride) {
        int4 p = *(const int4*)(pw + (size_t)i * 4);
        union { u16 s[8]; uint4 v; } o;
        int b;
        b = p.x; o.s[0] = f2bf((float)((b & 15) - 8)); o.s[1] = f2bf((float)(((b >> 4) & 15) - 8));
        b = p.y; o.s[2] = f2bf((float)((b & 15) - 8)); o.s[3] = f2bf((float)(((b >> 4) & 15) - 8));
        b = p.z; o.s[4] = f2bf((float)((b & 15) - 8)); o.s[5] = f2bf((float)(((b >> 4) & 15) - 8));
        b = p.w; o.s[6] = f2bf((float)((b & 15) - 8)); o.s[7] = f2bf((float)(((b >> 4) & 15) - 8));
        *(uint4*)(wb + (size_t)i * 8) = o.v;
    }
}

// ---------------------------------------------------------------------------
// Kernel 3: 256x256 8-phase bf16 GEMM (m201 template, strict staging schedule)
// C[n][o] = scale[o] * sum_k A[n][k]*B[o][k]
// ---------------------------------------------------------------------------
#define MFMA(a, b, c) __builtin_amdgcn_mfma_f32_16x16x32_bf16(a, b, c, 0, 0, 0)

static __device__ __forceinline__ short8 ldsv(const u16* p, int idx) {
    return *(const short8*)(p + idx);
}

// 16 MFMA: one C-quadrant (m-pair) x K=64
#define MFMA16(A0s0, A0s1, A1s0, A1s1, M0, M1)            \
    acc[M0][0] = MFMA(A0s0, b00, acc[M0][0]);             \
    acc[M0][1] = MFMA(A0s0, b10, acc[M0][1]);             \
    acc[M0][2] = MFMA(A0s0, b20, acc[M0][2]);             \
    acc[M0][3] = MFMA(A0s0, b30, acc[M0][3]);             \
    acc[M1][0] = MFMA(A1s0, b00, acc[M1][0]);             \
    acc[M1][1] = MFMA(A1s0, b10, acc[M1][1]);             \
    acc[M1][2] = MFMA(A1s0, b20, acc[M1][2]);             \
    acc[M1][3] = MFMA(A1s0, b30, acc[M1][3]);             \
    acc[M0][0] = MFMA(A0s1, b01, acc[M0][0]);             \
    acc[M0][1] = MFMA(A0s1, b11, acc[M0][1]);             \
    acc[M0][2] = MFMA(A0s1, b21, acc[M0][2]);             \
    acc[M0][3] = MFMA(A0s1, b31, acc[M0][3]);             \
    acc[M1][0] = MFMA(A1s1, b01, acc[M1][0]);             \
    acc[M1][1] = MFMA(A1s1, b11, acc[M1][1]);             \
    acc[M1][2] = MFMA(A1s1, b21, acc[M1][2]);             \
    acc[M1][3] = MFMA(A1s1, b31, acc[M1][3]);

__global__ __launch_bounds__(512, 2) void gemm8p_kernel(const u16* __restrict__ A,
                                                        const u16* __restrict__ B,
                                                        const float* __restrict__ scale,
                                                        float* __restrict__ C) {
    // 2 bufs x (A-lo, A-hi, B-lo, B-hi) x 8192 u16 (16KB each) = 128 KB
    __shared__ __align__(16) u16 lds[65536];

#define GLo(src, dstIdx)                                                        \
    __builtin_amdgcn_global_load_lds(                                           \
        (const __attribute__((address_space(1))) void*)(src),                   \
        (__attribute__((address_space(3))) void*)&lds[dstIdx], 16, 0, 0)

    // XCD-aware swizzle: nwg = 512, divisible by 8
    int wg = blockIdx.x;
    int swz = (wg & 7) * 64 + (wg >> 3);
    int bm = swz >> 4;       // 0..31
    int bn = swz & 15;       // 0..15

    int t = threadIdx.x;
    int l = t & 63;
    int wid = t >> 6;
    int wr = wid >> 2;       // 0..1  (128-row slab)
    int wc = wid & 3;        // 0..3  (64-col slab)

    // ---- staging source offsets: inverse st_16x32 swizzle of linear LDS dest ----
    // LDS region layout: subtile (rblk,kblk) of 16 rows x 32 cols (1024B),
    // within: r15*64B + (c2 ^ ((r15>>3)<<5)).
    size_t rowoff0, rowoff1;
    {
        int o = t * 16;
        int sb = o >> 10, rblk = sb >> 1, kblk = sb & 1;
        int w = o & 1023, r15 = w >> 6;
        int c2 = (w & 63) ^ (((w >> 9) & 1) << 5);
        rowoff0 = (size_t)(rblk * 16 + r15) * K_IN + kblk * 32 + (c2 >> 1);
        o = t * 16 + 8192;
        sb = o >> 10; rblk = sb >> 1; kblk = sb & 1;
        w = o & 1023; r15 = w >> 6;
        c2 = (w & 63) ^ (((w >> 9) & 1) << 5);
        rowoff1 = (size_t)(rblk * 16 + r15) * K_IN + kblk * 32 + (c2 >> 1);
    }
    const int t8 = t * 8;    // linear LDS dst (u16 units): t*16 bytes

    const u16* Alo = A + (size_t)(bm * 256) * K_IN;
    const u16* Ahi = Alo + (size_t)128 * K_IN;
    const u16* Blo = B + (size_t)(bn * 256) * K_IN;
    const u16* Bhi = Blo + (size_t)128 * K_IN;

    // ---- ds_read lane base (swizzled), u16 units ----
    int lbase = (l & 15) * 32 + (((l >> 4) * 8) ^ (((l >> 3) & 1) << 4));
    const int iA0 = wr * 8192 + lbase;
    const int iB0 = 16384 + (wc >> 1) * 8192 + (wc & 1) * 4096 + lbase;

    f32x4 acc[8][4] = {};

    // ---- prologue: tile0 (B-lo,B-hi,A-lo,A-hi) + B(1) ----
    GLo(Blo + rowoff0, 16384 + t8);        GLo(Blo + rowoff1, 16384 + t8 + 4096);
    GLo(Bhi + rowoff0, 24576 + t8);        GLo(Bhi + rowoff1, 24576 + t8 + 4096);
    GLo(Alo + rowoff0, t8);                GLo(Alo + rowoff1, t8 + 4096);
    GLo(Ahi + rowoff0, 8192 + t8);         GLo(Ahi + rowoff1, 8192 + t8 + 4096);
    GLo(Blo + rowoff0 + 64, 49152 + t8);   GLo(Blo + rowoff1 + 64, 49152 + t8 + 4096);
    GLo(Bhi + rowoff0 + 64, 57344 + t8);   GLo(Bhi + rowoff1 + 64, 57344 + t8 + 4096);
    asm volatile("s_waitcnt vmcnt(4)" ::: "memory");
    __builtin_amdgcn_s_barrier();

    for (int T = 0; T < NT; ++T) {
        const int buf = T & 1;
        const int iA = buf ? iA0 + 32768 : iA0;
        const int iB = buf ? iB0 + 32768 : iB0;

        // ================= phase 0: m0,m1; stage A(T+1) -> buf^1 =================
        short8 b00 = ldsv(lds, iB),        b01 = ldsv(lds, iB + 512);
        short8 b10 = ldsv(lds, iB + 1024), b11 = ldsv(lds, iB + 1536);
        short8 b20 = ldsv(lds, iB + 2048), b21 = ldsv(lds, iB + 2560);
        short8 b30 = ldsv(lds, iB + 3072), b31 = ldsv(lds, iB + 3584);
        short8 aP0 = ldsv(lds, iA),        aP1 = ldsv(lds, iA + 512);
        short8 aQ0 = ldsv(lds, iA + 1024), aQ1 = ldsv(lds, iA + 1536);
        if (T + 1 < NT) {
            size_t ko = (size_t)(T + 1) * 64;
            int d = (buf ^ 1) * 32768 + t8;
            GLo(Alo + rowoff0 + ko, d);         GLo(Alo + rowoff1 + ko, d + 4096);
            GLo(Ahi + rowoff0 + ko, d + 8192);  GLo(Ahi + rowoff1 + ko, d + 12288);
        }
        __builtin_amdgcn_s_barrier();
        asm volatile("s_waitcnt lgkmcnt(0)" ::: "memory");
        __builtin_amdgcn_s_setprio(1);
        MFMA16(aP0, aP1, aQ0, aQ1, 0, 1);
        __builtin_amdgcn_s_setprio(0);
        __builtin_amdgcn_s_barrier();

        // ================= phase 1: m2,m3; stage B-lo(T+2) -> buf =================
        aP0 = ldsv(lds, iA + 2048); aP1 = ldsv(lds, iA + 2560);
        aQ0 = ldsv(lds, iA + 3072); aQ1 = ldsv(lds, iA + 3584);
        if (T + 2 < NT) {
            size_t ko = (size_t)(T + 2) * 64;
            int d = buf * 32768 + 16384 + t8;
            GLo(Blo + rowoff0 + ko, d);  GLo(Blo + rowoff1 + ko, d + 4096);
        }
        __builtin_amdgcn_s_barrier();
        asm volatile("s_waitcnt lgkmcnt(0)" ::: "memory");
        __builtin_amdgcn_s_setprio(1);
        MFMA16(aP0, aP1, aQ0, aQ1, 2, 3);
        __builtin_amdgcn_s_setprio(0);
        __builtin_amdgcn_s_barrier();

        // ================= phase 2: m4,m5; stage B-hi(T+2) -> buf =================
        aP0 = ldsv(lds, iA + 4096); aP1 = ldsv(lds, iA + 4608);
        aQ0 = ldsv(lds, iA + 5120); aQ1 = ldsv(lds, iA + 5632);
        if (T + 2 < NT) {
            size_t ko = (size_t)(T + 2) * 64;
            int d = buf * 32768 + 24576 + t8;
            GLo(Bhi + rowoff0 + ko, d);  GLo(Bhi + rowoff1 + ko, d + 4096);
        }
        __builtin_amdgcn_s_barrier();
        asm volatile("s_waitcnt lgkmcnt(0)" ::: "memory");
        __builtin_amdgcn_s_setprio(1);
        MFMA16(aP0, aP1, aQ0, aQ1, 4, 5);
        __builtin_amdgcn_s_setprio(0);
        __builtin_amdgcn_s_barrier();

        // ================= phase 3: m6,m7; boundary vmcnt =================
        aP0 = ldsv(lds, iA + 6144); aP1 = ldsv(lds, iA + 6656);
        aQ0 = ldsv(lds, iA + 7168); aQ1 = ldsv(lds, iA + 7680);
        __builtin_amdgcn_s_barrier();
        asm volatile("s_waitcnt lgkmcnt(0)" ::: "memory");
        __builtin_amdgcn_s_setprio(1);
        MFMA16(aP0, aP1, aQ0, aQ1, 6, 7);
        __builtin_amdgcn_s_setprio(0);
        if (T < NT - 2) asm volatile("s_waitcnt vmcnt(4)" ::: "memory");
        else            asm volatile("s_waitcnt vmcnt(0)" ::: "memory");
        __builtin_amdgcn_s_barrier();
    }

    // ---- epilogue: C[row][col] = acc * scale[col] ----
    int col0 = bn * 256 + wc * 64 + (l & 15);
    float sc[4];
#pragma unroll
    for (int n = 0; n < 4; ++n) sc[n] = scale[col0 + n * 16];

#pragma unroll
    for (int m = 0; m < 8; ++m) {
        int row0 = bm * 256 + wr * 128 + m * 16 + (l >> 4) * 4;
#pragma unroll
        for (int n = 0; n < 4; ++n) {
            int gcol = col0 + n * 16;
#pragma unroll
            for (int j = 0; j < 4; ++j)
                C[(size_t)(row0 + j) * N_OUT + gcol] = acc[m][n][j] * sc[n];
        }
    }
#undef GLo
}

// ---------------------------------------------------------------------------
// Fallback (workspace too small): fused fp32 LDS-tiled GEMM
// ---------------------------------------------------------------------------
__global__ __launch_bounds__(256) void gemm_fb_kernel(const float* __restrict__ X,
                                                      const int* __restrict__ PW,
                                                      const float* __restrict__ S,
                                                      float* __restrict__ C) {
    __shared__ float sx[64][33];
    __shared__ float sw[64][33];
    int bm = blockIdx.x / (N_OUT / 64);
    int bn = blockIdx.x % (N_OUT / 64);
    int t = threadIdx.x;
    int r = t >> 2, c8 = (t & 3) * 8;
    int tx = t & 15, ty = t >> 4;
    float acc[4][4] = {};
    for (int k0 = 0; k0 < K_IN; k0 += 32) {
        const float* xs = X + (size_t)(bm * 64 + r) * K_IN + k0 + c8;
#pragma unroll
        for (int j = 0; j < 8; ++j) sx[r][c8 + j] = xs[j];
        const int* ps = PW + ((size_t)(bn * 64 + r) * K_IN + k0 + c8) / 2;
#pragma unroll
        for (int j = 0; j < 4; ++j) {
            int b = ps[j];
            sw[r][c8 + 2 * j]     = (float)((b & 15) - 8);
            sw[r][c8 + 2 * j + 1] = (float)(((b >> 4) & 15) - 8);
        }
        __syncthreads();
#pragma unroll
        for (int kk = 0; kk < 32; ++kk) {
            float a[4], w[4];
#pragma unroll
            for (int i = 0; i < 4; ++i) a[i] = sx[ty * 4 + i][kk];
#pragma unroll
            for (int j = 0; j < 4; ++j) w[j] = sw[tx * 4 + j][kk];
#pragma unroll
            for (int i = 0; i < 4; ++i)
#pragma unroll
                for (int j = 0; j < 4; ++j) acc[i][j] += a[i] * w[j];
        }
        __syncthreads();
    }
#pragma unroll
    for (int i = 0; i < 4; ++i) {
        int gr = bm * 64 + ty * 4 + i;
#pragma unroll
        for (int j = 0; j < 4; ++j) {
            int gc = bn * 64 + tx * 4 + j;
            C[(size_t)gr * N_OUT + gc] = acc[i][j] * S[gc];
        }
    }
}

// ---------------------------------------------------------------------------
// Entry point
// ---------------------------------------------------------------------------
extern "C" void kernel_launch(void* const* d_in, const int* in_sizes, int n_in,
                              void* d_out, int out_size, void* d_ws, size_t ws_size,
                              hipStream_t stream) {
    const float* x  = (const float*)d_in[0];
    const int*   pw = (const int*)d_in[1];
    const float* sc = (const float*)d_in[2];
    float* out = (float*)d_out;

    const size_t xb_elems = (size_t)M_TOK * K_IN;
    const size_t wb_elems = (size_t)N_OUT * K_IN;
    const size_t need = (xb_elems + wb_elems) * sizeof(u16);

    if (ws_size >= need) {
        u16* xb = (u16*)d_ws;
        u16* wb = xb + xb_elems;
        cvt_x_kernel<<<dim3(2048), dim3(256), 0, stream>>>(x, xb, (int)(xb_elems / 8));
        unpack_w_kernel<<<dim3(2048), dim3(256), 0, stream>>>(pw, wb, (int)(wb_elems / 8));
        gemm8p_kernel<<<dim3((M_TOK / 256) * (N_OUT / 256)), dim3(512), 0, stream>>>(xb, wb, sc, out);
    } else {
        gemm_fb_kernel<<<dim3((M_TOK / 64) * (N_OUT / 64)), dim3(256), 0, stream>>>(x, pw, sc, out);
    }
}

// Round 3
// 170.572 us; speedup vs baseline: 2.1255x; 1.5843x over previous
//
#include <hip/hip_runtime.h>

typedef unsigned char u8;
typedef signed char s8;
typedef unsigned int u32;
typedef __attribute__((ext_vector_type(4))) int i32x4;

#define M_TOK 8192
#define N_OUT 4096
#define K_IN  4096
#define NT    32          // K-tiles of BK=128 int8

// ---------------------------------------------------------------------------
// Kernel 1: per-row absmax quantize x fp32 -> int8, one block per row
// ---------------------------------------------------------------------------
static __device__ __forceinline__ u32 pack4(float4 v, float inv) {
    int q0 = __float2int_rn(v.x * inv) & 255;
    int q1 = __float2int_rn(v.y * inv) & 255;
    int q2 = __float2int_rn(v.z * inv) & 255;
    int q3 = __float2int_rn(v.w * inv) & 255;
    return (u32)q0 | ((u32)q1 << 8) | ((u32)q2 << 16) | ((u32)q3 << 24);
}

__global__ __launch_bounds__(256) void quant_x_kernel(const float* __restrict__ x,
                                                      s8* __restrict__ xq,
                                                      float* __restrict__ sx) {
    int row = blockIdx.x;
    int t = threadIdx.x;
    const float4* xr = (const float4*)(x + (size_t)row * K_IN);
    float4 v0 = xr[t], v1 = xr[t + 256], v2 = xr[t + 512], v3 = xr[t + 768];
    float am = 0.f;
    am = fmaxf(am, fmaxf(fmaxf(fabsf(v0.x), fabsf(v0.y)), fmaxf(fabsf(v0.z), fabsf(v0.w))));
    am = fmaxf(am, fmaxf(fmaxf(fabsf(v1.x), fabsf(v1.y)), fmaxf(fabsf(v1.z), fabsf(v1.w))));
    am = fmaxf(am, fmaxf(fmaxf(fabsf(v2.x), fabsf(v2.y)), fmaxf(fabsf(v2.z), fabsf(v2.w))));
    am = fmaxf(am, fmaxf(fmaxf(fabsf(v3.x), fabsf(v3.y)), fmaxf(fabsf(v3.z), fabsf(v3.w))));
#pragma unroll
    for (int o = 32; o > 0; o >>= 1) am = fmaxf(am, __shfl_xor(am, o));
    __shared__ float red[4];
    if ((t & 63) == 0) red[t >> 6] = am;
    __syncthreads();
    am = fmaxf(fmaxf(red[0], red[1]), fmaxf(red[2], red[3]));
    float inv = (am > 0.f) ? 127.f / am : 0.f;
    if (t == 0) sx[row] = (am > 0.f) ? am / 127.f : 0.f;
    u32* out = (u32*)(xq + (size_t)row * K_IN);
    out[t]       = pack4(v0, inv);
    out[t + 256] = pack4(v1, inv);
    out[t + 512] = pack4(v2, inv);
    out[t + 768] = pack4(v3, inv);
}

// ---------------------------------------------------------------------------
// Kernel 2: unpack int4 (one byte per int32) -> int8 [O][I]
// ---------------------------------------------------------------------------
__global__ __launch_bounds__(256) void unpack_w_kernel(const int* __restrict__ pw,
                                                       s8* __restrict__ wq, int n4) {
    int idx = blockIdx.x * blockDim.x + threadIdx.x;
    int stride = gridDim.x * blockDim.x;
    for (int i = idx; i < n4; i += stride) {
        int4 p = *(const int4*)(pw + (size_t)i * 4);
        u32 lo = (u32)(((p.x & 15) - 8) & 255)
               | ((u32)((((p.x >> 4) & 15) - 8) & 255) << 8)
               | ((u32)((((p.y) & 15) - 8) & 255) << 16)
               | ((u32)((((p.y >> 4) & 15) - 8) & 255) << 24);
        u32 hi = (u32)(((p.z & 15) - 8) & 255)
               | ((u32)((((p.z >> 4) & 15) - 8) & 255) << 8)
               | ((u32)((((p.w) & 15) - 8) & 255) << 16)
               | ((u32)((((p.w >> 4) & 15) - 8) & 255) << 24);
        uint2 o; o.x = lo; o.y = hi;
        *(uint2*)(wq + (size_t)i * 8) = o;
    }
}

// ---------------------------------------------------------------------------
// Kernel 3: 256x256 8-phase int8 GEMM (round-2 schedule, i8 K=64 MFMA)
// C[n][o] = sx[n] * scale[o] * sum_k xq[n][k]*wq[o][k]   (exact i32 dot)
// LDS: row-major [256][128] i8 per operand region, byte ^= (row&7)<<4 swizzle.
// ---------------------------------------------------------------------------
#define MFMA(a, b, c) __builtin_amdgcn_mfma_i32_16x16x64_i8(a, b, c, 0, 0, 0)

static __device__ __forceinline__ i32x4 ldsv(const u8* p, int idx) {
    return *(const i32x4*)(p + idx);
}

#define MFMA16(A00, A01, A10, A11, M0, M1)                \
    acc[M0][0] = MFMA(A00, b00, acc[M0][0]);              \
    acc[M0][1] = MFMA(A00, b10, acc[M0][1]);              \
    acc[M0][2] = MFMA(A00, b20, acc[M0][2]);              \
    acc[M0][3] = MFMA(A00, b30, acc[M0][3]);              \
    acc[M1][0] = MFMA(A10, b00, acc[M1][0]);              \
    acc[M1][1] = MFMA(A10, b10, acc[M1][1]);              \
    acc[M1][2] = MFMA(A10, b20, acc[M1][2]);              \
    acc[M1][3] = MFMA(A10, b30, acc[M1][3]);              \
    acc[M0][0] = MFMA(A01, b01, acc[M0][0]);              \
    acc[M0][1] = MFMA(A01, b11, acc[M0][1]);              \
    acc[M0][2] = MFMA(A01, b21, acc[M0][2]);              \
    acc[M0][3] = MFMA(A01, b31, acc[M0][3]);              \
    acc[M1][0] = MFMA(A11, b01, acc[M1][0]);              \
    acc[M1][1] = MFMA(A11, b11, acc[M1][1]);              \
    acc[M1][2] = MFMA(A11, b21, acc[M1][2]);              \
    acc[M1][3] = MFMA(A11, b31, acc[M1][3]);

__global__ __launch_bounds__(512, 2) void gemm8p_i8_kernel(const s8* __restrict__ A,
                                                           const s8* __restrict__ B,
                                                           const float* __restrict__ sx,
                                                           const float* __restrict__ scale,
                                                           float* __restrict__ C) {
    // 2 bufs x (A 32KB + B 32KB) = 128 KB
    __shared__ __align__(16) u8 lds[131072];

#define GLo(src, dstIdx)                                                        \
    __builtin_amdgcn_global_load_lds(                                           \
        (const __attribute__((address_space(1))) void*)(src),                   \
        (__attribute__((address_space(3))) void*)&lds[dstIdx], 16, 0, 0)

    // XCD-aware swizzle: nwg = 512, divisible by 8
    int wg = blockIdx.x;
    int swz = (wg & 7) * 64 + (wg >> 3);
    int bm = swz >> 4;       // 0..31
    int bn = swz & 15;       // 0..15

    int t = threadIdx.x;
    int l = t & 63;
    int wid = t >> 6;
    int wr = wid >> 2;       // 0..1  (128-row slab of A)
    int wc = wid & 3;        // 0..3  (64-row slab of B = 64 output cols)

    // staging: dest byte = t*16 (linear); dest row = t>>3, col = (t&7)*16.
    // source col = destcol ^ ((row&7)<<4)  (inverse of read-side swizzle)
    const size_t soff = (size_t)(t >> 3) * K_IN + (size_t)((((t & 7) ^ ((t >> 3) & 7)) << 4));
    const size_t S64 = (size_t)64 * K_IN;   // +64 rows
    const int t16 = t * 16;

    const s8* Alo = A + (size_t)(bm * 256) * K_IN;
    const s8* Ahi = Alo + (size_t)128 * K_IN;
    const s8* Blo = B + (size_t)(bn * 256) * K_IN;
    const s8* Bhi = Blo + (size_t)128 * K_IN;

    // ds_read fragment addressing (bytes): row-major 256x128 + XOR swizzle
    const int kx = (l & 7) << 4;
    const int koff0 = (((l >> 4) << 4)) ^ kx;   // K-half 0
    const int koff1 = koff0 ^ 64;               // K-half 1
    const int aB = wr * 16384 + (l & 15) * 128;           // within A region
    const int bB = 32768 + wc * 8192 + (l & 15) * 128;    // within B region

    i32x4 acc[8][4] = {};

    // ---- prologue: tile0 (B, A) -> buf0, B(1) -> buf1 ----
    GLo(Blo + soff, 32768 + t16);         GLo(Blo + soff + S64, 32768 + t16 + 8192);
    GLo(Bhi + soff, 49152 + t16);         GLo(Bhi + soff + S64, 49152 + t16 + 8192);
    GLo(Alo + soff, t16);                 GLo(Alo + soff + S64, t16 + 8192);
    GLo(Ahi + soff, 16384 + t16);         GLo(Ahi + soff + S64, 16384 + t16 + 8192);
    GLo(Blo + soff + 128, 98304 + t16);   GLo(Blo + soff + S64 + 128, 98304 + t16 + 8192);
    GLo(Bhi + soff + 128, 114688 + t16);  GLo(Bhi + soff + S64 + 128, 114688 + t16 + 8192);
    asm volatile("s_waitcnt vmcnt(4)" ::: "memory");
    __builtin_amdgcn_s_barrier();

    for (int T = 0; T < NT; ++T) {
        const int buf = T & 1;
        const u8* L = lds + buf * 65536;

        // ============ phase 0: m0,m1; stage A(T+1) -> buf^1 ============
        i32x4 b00 = ldsv(L, bB + koff0),        b01 = ldsv(L, bB + koff1);
        i32x4 b10 = ldsv(L, bB + 2048 + koff0), b11 = ldsv(L, bB + 2048 + koff1);
        i32x4 b20 = ldsv(L, bB + 4096 + koff0), b21 = ldsv(L, bB + 4096 + koff1);
        i32x4 b30 = ldsv(L, bB + 6144 + koff0), b31 = ldsv(L, bB + 6144 + koff1);
        i32x4 a00 = ldsv(L, aB + koff0),        a01 = ldsv(L, aB + koff1);
        i32x4 a10 = ldsv(L, aB + 2048 + koff0), a11 = ldsv(L, aB + 2048 + koff1);
        if (T + 1 < NT) {
            size_t ko = (size_t)(T + 1) * 128;
            int d = (buf ^ 1) * 65536 + t16;
            GLo(Alo + soff + ko, d);                 GLo(Alo + soff + S64 + ko, d + 8192);
            GLo(Ahi + soff + ko, d + 16384);         GLo(Ahi + soff + S64 + ko, d + 24576);
        }
        __builtin_amdgcn_s_barrier();
        asm volatile("s_waitcnt lgkmcnt(0)" ::: "memory");
        __builtin_amdgcn_s_setprio(1);
        MFMA16(a00, a01, a10, a11, 0, 1);
        __builtin_amdgcn_s_setprio(0);
        __builtin_amdgcn_s_barrier();

        // ============ phase 1: m2,m3; stage B-lo(T+2) -> buf ============
        a00 = ldsv(L, aB + 4096 + koff0); a01 = ldsv(L, aB + 4096 + koff1);
        a10 = ldsv(L, aB + 6144 + koff0); a11 = ldsv(L, aB + 6144 + koff1);
        if (T + 2 < NT) {
            size_t ko = (size_t)(T + 2) * 128;
            int d = buf * 65536 + 32768 + t16;
            GLo(Blo + soff + ko, d);  GLo(Blo + soff + S64 + ko, d + 8192);
        }
        __builtin_amdgcn_s_barrier();
        asm volatile("s_waitcnt lgkmcnt(0)" ::: "memory");
        __builtin_amdgcn_s_setprio(1);
        MFMA16(a00, a01, a10, a11, 2, 3);
        __builtin_amdgcn_s_setprio(0);
        __builtin_amdgcn_s_barrier();

        // ============ phase 2: m4,m5; stage B-hi(T+2) -> buf ============
        a00 = ldsv(L, aB + 8192 + koff0);  a01 = ldsv(L, aB + 8192 + koff1);
        a10 = ldsv(L, aB + 10240 + koff0); a11 = ldsv(L, aB + 10240 + koff1);
        if (T + 2 < NT) {
            size_t ko = (size_t)(T + 2) * 128;
            int d = buf * 65536 + 49152 + t16;
            GLo(Bhi + soff + ko, d);  GLo(Bhi + soff + S64 + ko, d + 8192);
        }
        __builtin_amdgcn_s_barrier();
        asm volatile("s_waitcnt lgkmcnt(0)" ::: "memory");
        __builtin_amdgcn_s_setprio(1);
        MFMA16(a00, a01, a10, a11, 4, 5);
        __builtin_amdgcn_s_setprio(0);
        __builtin_amdgcn_s_barrier();

        // ============ phase 3: m6,m7; boundary vmcnt ============
        a00 = ldsv(L, aB + 12288 + koff0); a01 = ldsv(L, aB + 12288 + koff1);
        a10 = ldsv(L, aB + 14336 + koff0); a11 = ldsv(L, aB + 14336 + koff1);
        __builtin_amdgcn_s_barrier();
        asm volatile("s_waitcnt lgkmcnt(0)" ::: "memory");
        __builtin_amdgcn_s_setprio(1);
        MFMA16(a00, a01, a10, a11, 6, 7);
        __builtin_amdgcn_s_setprio(0);
        if (T < NT - 2) asm volatile("s_waitcnt vmcnt(4)" ::: "memory");
        else            asm volatile("s_waitcnt vmcnt(0)" ::: "memory");
        __builtin_amdgcn_s_barrier();
    }

    // ---- epilogue: C[row][col] = acc * sx[row] * scale[col] ----
    int col0 = bn * 256 + wc * 64 + (l & 15);
    float sc_[4];
#pragma unroll
    for (int n = 0; n < 4; ++n) sc_[n] = scale[col0 + n * 16];

#pragma unroll
    for (int m = 0; m < 8; ++m) {
        int row0 = bm * 256 + wr * 128 + m * 16 + (l >> 4) * 4;
        float4 sxr = *(const float4*)(sx + row0);
        float sxa[4] = {sxr.x, sxr.y, sxr.z, sxr.w};
#pragma unroll
        for (int n = 0; n < 4; ++n) {
            int gcol = col0 + n * 16;
#pragma unroll
            for (int j = 0; j < 4; ++j)
                C[(size_t)(row0 + j) * N_OUT + gcol] = (float)acc[m][n][j] * sxa[j] * sc_[n];
        }
    }
#undef GLo
}

// ---------------------------------------------------------------------------
// Fallback (workspace too small): fused fp32 LDS-tiled GEMM
// ---------------------------------------------------------------------------
__global__ __launch_bounds__(256) void gemm_fb_kernel(const float* __restrict__ X,
                                                      const int* __restrict__ PW,
                                                      const float* __restrict__ S,
                                                      float* __restrict__ C) {
    __shared__ float sxm[64][33];
    __shared__ float swm[64][33];
    int bm = blockIdx.x / (N_OUT / 64);
    int bn = blockIdx.x % (N_OUT / 64);
    int t = threadIdx.x;
    int r = t >> 2, c8 = (t & 3) * 8;
    int tx = t & 15, ty = t >> 4;
    float acc[4][4] = {};
    for (int k0 = 0; k0 < K_IN; k0 += 32) {
        const float* xs = X + (size_t)(bm * 64 + r) * K_IN + k0 + c8;
#pragma unroll
        for (int j = 0; j < 8; ++j) sxm[r][c8 + j] = xs[j];
        const int* ps = PW + ((size_t)(bn * 64 + r) * K_IN + k0 + c8) / 2;
#pragma unroll
        for (int j = 0; j < 4; ++j) {
            int b = ps[j];
            swm[r][c8 + 2 * j]     = (float)((b & 15) - 8);
            swm[r][c8 + 2 * j + 1] = (float)(((b >> 4) & 15) - 8);
        }
        __syncthreads();
#pragma unroll
        for (int kk = 0; kk < 32; ++kk) {
            float a[4], w[4];
#pragma unroll
            for (int i = 0; i < 4; ++i) a[i] = sxm[ty * 4 + i][kk];
#pragma unroll
            for (int j = 0; j < 4; ++j) w[j] = swm[tx * 4 + j][kk];
#pragma unroll
            for (int i = 0; i < 4; ++i)
#pragma unroll
                for (int j = 0; j < 4; ++j) acc[i][j] += a[i] * w[j];
        }
        __syncthreads();
    }
#pragma unroll
    for (int i = 0; i < 4; ++i) {
        int gr = bm * 64 + ty * 4 + i;
#pragma unroll
        for (int j = 0; j < 4; ++j) {
            int gc = bn * 64 + tx * 4 + j;
            C[(size_t)gr * N_OUT + gc] = acc[i][j] * S[gc];
        }
    }
}

// ---------------------------------------------------------------------------
// Entry point
// ---------------------------------------------------------------------------
extern "C" void kernel_launch(void* const* d_in, const int* in_sizes, int n_in,
                              void* d_out, int out_size, void* d_ws, size_t ws_size,
                              hipStream_t stream) {
    const float* x  = (const float*)d_in[0];
    const int*   pw = (const int*)d_in[1];
    const float* sc = (const float*)d_in[2];
    float* out = (float*)d_out;

    const size_t xq_bytes = (size_t)M_TOK * K_IN;        // 33.5 MB
    const size_t wq_bytes = (size_t)N_OUT * K_IN;        // 16.8 MB
    const size_t sx_bytes = (size_t)M_TOK * sizeof(float);
    const size_t need = xq_bytes + wq_bytes + sx_bytes;

    if (ws_size >= need) {
        s8* xq = (s8*)d_ws;
        s8* wq = xq + xq_bytes;
        float* sx = (float*)(wq + wq_bytes);
        quant_x_kernel<<<dim3(M_TOK), dim3(256), 0, stream>>>(x, xq, sx);
        unpack_w_kernel<<<dim3(2048), dim3(256), 0, stream>>>(pw, wq,
                                                              (int)(((size_t)N_OUT * K_IN / 2) / 4));
        gemm8p_i8_kernel<<<dim3((M_TOK / 256) * (N_OUT / 256)), dim3(512), 0, stream>>>(
            xq, wq, sx, sc, out);
    } else {
        gemm_fb_kernel<<<dim3((M_TOK / 64) * (N_OUT / 64)), dim3(256), 0, stream>>>(x, pw, sc, out);
    }
}